// Round 7
// baseline (728270.508 us; speedup 1.0000x reference)
//
#include <hip/hip_runtime.h>
#include <cmath>

// TimeLSTMCell B=64, S=512, E=256, H=512.
// Round 11 (base = round-6 @2008us verbatim; r10's 4-lever bundle regressed
// and is fully reverted). ONE lever: XCD-LOCAL EXCHANGE.
//   * NWG=128: 8 groups x 16 WGs; group = blockIdx&7 (XCD residue under
//     round-robin dispatch), cg = blockIdx>>3. Each group owns 8 batches.
//     Per-WG MFMA count unchanged (rows 8-15 of LDS tiles stay zero).
//   * Startup bulletin: each WG posts s_getreg(HW_REG_XCC_ID) (m09-verified);
//     a group whose 16 members share one XCD switches mirror+flag traffic to
//     that XCD's L2: plain write-through stores + sc0 (L1-bypass) loads,
//     ~250-350cy RT vs ~900-1200cy MALL. Impure groups use the r6 agent-scope
//     path unchanged -> correctness never depends on placement (G16).
//   * All polls iteration-capped: a wrong detection degrades to a visible
//     correctness failure, never a hang.
// Everything else (5-barrier skeleton, decv, out-store-in-finale, mirror
// format, weights-in-VGPR, frag layouts, numerics) is round-6 verbatim.
//
// Fast-path coherence argument: producer mirror stores are write-through to
// its XCD L2; barrier B's implicit vmcnt(0) drains them; flag store follows;
// consumer (same XCD) polls flag with sc0 (L1-bypassed, L2-served) and then
// sc0-loads mirrors -> data already in the same L2. No cross-XCD traffic.
//
// MFMA 16x16x32 bf16 layouts (m89/m91/m120 verified):
//   A: m=lane&15, k=(lane>>4)*8+j   B: n=lane&15, k=(lane>>4)*8+j
//   D: n=lane&15, m=(lane>>4)*4+reg

typedef short bf16x8 __attribute__((ext_vector_type(8)));
typedef float f32x4  __attribute__((ext_vector_type(4)));

#define Bdim 64
#define Sdim 512
#define Edim 256
#define Hdim 512
#define NWG  128
#define NT   512
#define FSTR 16
#define FPOLL_CAP 16384
#define BULL_CAP  65536

// ws layout (bytes). Total ~3.95 MB.
#define WS_FLAGS 0                        // 128 flags * FSTR ints = 8192 B
#define WS_BULL  8192                     // bulletin: 128 u32
#define WS_HMIR0 16384
#define WS_HMIR1 (WS_HMIR0 + 65536)
#define WS_CMIR0 (WS_HMIR1 + 65536)
#define WS_CMIR1 (WS_CMIR0 + 65536)
#define WS_WFRAG (WS_CMIR1 + 65536)       // 16cg*8wv*24k*64lane*8 bf16 = 3 MB
#define WS_DFRAG (WS_WFRAG + 3145728)     // 16cg*8wv*4k*64lane*8 bf16 = 512 KB

__device__ __forceinline__ unsigned ld_dev_u32(const unsigned* p) {
    return __hip_atomic_load(p, __ATOMIC_RELAXED, __HIP_MEMORY_SCOPE_AGENT);
}
__device__ __forceinline__ void st_dev_u32(unsigned* p, unsigned v) {
    __hip_atomic_store(p, v, __ATOMIC_RELAXED, __HIP_MEMORY_SCOPE_AGENT);
}
__device__ __forceinline__ unsigned long long ld_dev_u64(const unsigned long long* p) {
    return __hip_atomic_load(p, __ATOMIC_RELAXED, __HIP_MEMORY_SCOPE_AGENT);
}
// XCD-L2 fast path: sc0 load (L1 bypass, L2 served), single-use w/ wait.
__device__ __forceinline__ unsigned ld_l2_u32(const unsigned* p) {
    unsigned r;
    asm volatile("global_load_dword %0, %1, off sc0\n\ts_waitcnt vmcnt(0)"
                 : "=v"(r) : "v"(p) : "memory");
    return r;
}
__device__ __forceinline__ unsigned short f2bf(float f) {
    union { float f; unsigned u; } v; v.f = f;
    return (unsigned short)((v.u + 0x7FFFu + ((v.u >> 16) & 1u)) >> 16);  // RNE
}
__device__ __forceinline__ unsigned pack2(float lo, float hi) {
    return (unsigned)f2bf(lo) | ((unsigned)f2bf(hi) << 16);
}
__device__ __forceinline__ float fast_tanh(float x) {
    const float ax = __builtin_fabsf(x);
    const float e  = __expf(-2.0f * ax);
    const float t  = (1.0f - e) / (1.0f + e);
    return __builtin_copysignf(t, x);
}
__device__ __forceinline__ float fast_sigmoid(float x) {
    return 1.0f / (1.0f + __expf(-x));
}

// ---------------- pre-pass: pack weights, zero mirrors/flags ----------------
// (verbatim round 6 — frag layouts unchanged)
__global__ __launch_bounds__(256) void tlstm_prep(
    const float* __restrict__ Wall, const float* __restrict__ Uall,
    const float* __restrict__ Wd, unsigned char* __restrict__ ws)
{
    const int w = blockIdx.x, t = threadIdx.x;
    unsigned short* Wfrag = (unsigned short*)(ws + WS_WFRAG);
    unsigned short* Dfrag = (unsigned short*)(ws + WS_DFRAG);
    const int l = t & 63, ks = t >> 6, nn = l & 15, q = l >> 4;

    if (w < 128) {                       // gate fragments: WG = (cg, wv)
        const int cg = w >> 3, wv = w & 7;
        const int G = wv * 16 + nn, g = G >> 5, jj = G & 31;
        const int row = g * Hdim + cg * 32 + jj;
        for (int i = 0; i < 6; ++i) {
            const int kp = ks * 6 + i;   // 0..23
            const float* src = (kp < 16)
                ? Wall + (size_t)row * Hdim + kp * 32 + q * 8
                : Uall + (size_t)row * Edim + (kp - 16) * 32 + q * 8;
            unsigned* dst = (unsigned*)(Wfrag
                + (((size_t)(cg * 8 + wv) * 24 + kp) * 64 + l) * 8);
            #pragma unroll
            for (int p = 0; p < 4; ++p) dst[p] = pack2(src[2*p], src[2*p+1]);
        }
    } else if (w < 192) {                // d fragments: 64 WGs, 8 frags each
        const int u = w - 128, cg = u >> 2, q4 = u & 3;
        for (int half = 0; half < 2; ++half) {
            const int wv = q4 * 2 + half;        // 0..7
            const int i  = ks;                   // 0..3
            const int dt = wv >> 2, kd = (wv & 3) * 4 + i;
            const int row = cg * 32 + dt * 16 + nn;     // Wd output col
            const float* src = Wd + (size_t)row * Hdim + kd * 32 + q * 8;
            unsigned* dst = (unsigned*)(Dfrag
                + (((size_t)(cg * 8 + wv) * 4 + i) * 64 + l) * 8);
            #pragma unroll
            for (int p = 0; p < 4; ++p) dst[p] = pack2(src[2*p], src[2*p+1]);
        }
    } else {                             // zero flags+bulletin+mirrors (272 KB)
        const int idx = (w - 192) * 256 + t;          // 0..16383
        uint4* z = (uint4*)ws;
        for (int i = idx; i < 17408; i += 16384) z[i] = make_uint4(0, 0, 0, 0);
        // mirror parity-0 zeros ARE the valid step-0 state (h=c=0).
    }
}

// ------------------------------- main kernel --------------------------------
__global__ __launch_bounds__(NT, 2) void tlstm_mfma(
    const float* __restrict__ x,       // [B,S,E] fp32
    const float* __restrict__ ts,      // [B,S]
    const float* __restrict__ Wall_b,  // [4H]
    const float* __restrict__ Uall_b,  // [4H]
    const float* __restrict__ Wd_b,    // [H]
    float* __restrict__ out,           // [B,S,H] | h_f | c_f (write-only)
    unsigned char* __restrict__ ws)
{
    __shared__ __align__(16) unsigned short h_sb[16 * 520];   // rows 8-15 stay 0
    __shared__ __align__(16) unsigned short c_sb[16 * 520];
    __shared__ __align__(16) unsigned short x_sb[16 * 264];
    __shared__ float Dred[2][4][256];
    __shared__ float act[4 * 512];              // [gate][m*32+jj]
    __shared__ float cs1v[512];
    __shared__ float decv[16];
    __shared__ int fast_sh;

    int* flags = (int*)(ws + WS_FLAGS);
    const unsigned short* Wfrag = (const unsigned short*)(ws + WS_WFRAG);
    const unsigned short* Dfrag = (const unsigned short*)(ws + WS_DFRAG);

    const int t    = threadIdx.x;
    const int bg   = blockIdx.x & 7, cg = blockIdx.x >> 3;   // group = XCD residue
    const int b0   = bg * 8, j0 = cg * 32;                   // 8 batches/group
    const int w    = t >> 6, lane = t & 63, q = lane >> 4, nn = lane & 15;

    // ---- startup: bulletin -> is this group XCD-pure? ----
    unsigned xcd;
    asm volatile("s_getreg_b32 %0, hwreg(HW_REG_XCC_ID)" : "=s"(xcd));
    if (t == 0) {
        unsigned* bul = (unsigned*)(ws + WS_BULL);
        st_dev_u32(&bul[bg * 16 + cg], xcd + 1);
        bool ok = true; unsigned v0 = 0;
        for (int i = 0; i < 16; ++i) {
            unsigned vi = 0;
            for (int it = 0; it < BULL_CAP; ++it) {
                vi = ld_dev_u32(&bul[bg * 16 + i]);
                if (vi) break;
                __builtin_amdgcn_s_sleep(8);
            }
            if (i == 0) v0 = vi;
            ok = ok && (vi != 0) && (vi == v0);
        }
        fast_sh = ok ? 1 : 0;
    }
    __syncthreads();
    const bool fast = (fast_sh != 0);

    // gate-col identity of this lane (wave w owns gate-col tile w: 16 cols)
    const int G = w * 16 + nn, g = G >> 5, jj = G & 31;
    const float bias_g = Wall_b[g * Hdim + j0 + jj] + Uall_b[g * Hdim + j0 + jj];
    // d-reduce identity (thread-indexed; r6 verbatim)
    const int rtl = t >> 8, rpos = t & 255, rm = rpos >> 4, rn = rpos & 15;
    const float bias_d = Wd_b[j0 + rtl * 16 + rn];
    // finale identity: unit t -> (batch fm, col fj); only t<256 active (8 rows)
    const int fm = t >> 5, fj = t & 31;

    // ---- weights -> registers, once (L2-hot loads; r6 layout) ----
    bf16x8 bw[24];
    #pragma unroll
    for (int i = 0; i < 24; ++i)
        bw[i] = *(const bf16x8*)(Wfrag
            + (((size_t)(cg * 8 + w) * 24 + i) * 64 + lane) * 8);
    bf16x8 bd[4];
    #pragma unroll
    for (int i = 0; i < 4; ++i)
        bd[i] = *(const bf16x8*)(Dfrag
            + (((size_t)(cg * 8 + w) * 4 + i) * 64 + lane) * 8);

    const int srow = t >> 5, sc32 = t & 31;    // staging role (t<256: rows 0..7)

    // stage x[b0..b0+8, sx, :] -> x_sb rows 0..7 (cached loads, fp32 -> bf16)
    auto stage_x = [&](int sx) {
        const float4* xp = (const float4*)(x + ((size_t)(b0 + srow) * Sdim + sx) * Edim + sc32 * 8);
        float4 v0 = xp[0], v1 = xp[1];
        *(uint4*)((unsigned*)x_sb + srow * 132 + sc32 * 4) =
            make_uint4(pack2(v0.x, v0.y), pack2(v0.z, v0.w),
                       pack2(v1.x, v1.y), pack2(v1.z, v1.w));
    };

    // ---- prologue: zero all LDS tiles (rows 8-15 stay zero forever) ----
    for (int i = t; i < 16 * 520; i += NT) { h_sb[i] = 0; c_sb[i] = 0; }
    for (int i = t; i < 16 * 264; i += NT) x_sb[i] = 0;
    __syncthreads();
    if (t < 256) stage_x(0);
    float c_reg = 0.0f;                        // fp32 c carry for own unit
    __syncthreads();

    for (int s = 0;; ++s) {
        // ---- stage h, c rows 0..7 (bf16 mirrors) ----
        if (t < 256) {
            const unsigned long long* hsrc =
                (const unsigned long long*)(ws + WS_HMIR0 + (s & 1) * 65536);
            const unsigned long long* csrc =
                (const unsigned long long*)(ws + WS_CMIR0 + (s & 1) * 65536);
            const size_t goff = (size_t)(b0 + srow) * 128 + sc32 * 4;  // u64 idx
            unsigned long long hv[4], cv[4];
            if (fast) {      // sc0 loads: batched issue, one wait (rule 18)
                #pragma unroll
                for (int i = 0; i < 4; ++i)
                    asm volatile("global_load_dwordx2 %0, %1, off sc0"
                                 : "=v"(hv[i]) : "v"(hsrc + goff + i));
                #pragma unroll
                for (int i = 0; i < 4; ++i)
                    asm volatile("global_load_dwordx2 %0, %1, off sc0"
                                 : "=v"(cv[i]) : "v"(csrc + goff + i));
                asm volatile("s_waitcnt vmcnt(0)" ::: "memory");
                __builtin_amdgcn_sched_barrier(0);
            } else {         // MALL fallback (r6 semantics)
                #pragma unroll
                for (int i = 0; i < 4; ++i) hv[i] = ld_dev_u64(hsrc + goff + i);
                #pragma unroll
                for (int i = 0; i < 4; ++i) cv[i] = ld_dev_u64(csrc + goff + i);
            }
            unsigned* hls = (unsigned*)h_sb + srow * 260 + sc32 * 8;
            unsigned* cls = (unsigned*)c_sb + srow * 260 + sc32 * 8;
            ((ulonglong2*)hls)[0] = make_ulonglong2(hv[0], hv[1]);
            ((ulonglong2*)hls)[1] = make_ulonglong2(hv[2], hv[3]);
            ((ulonglong2*)cls)[0] = make_ulonglong2(cv[0], cv[1]);
            ((ulonglong2*)cls)[1] = make_ulonglong2(cv[2], cv[3]);
        }
        __syncthreads();

        // ---- MFMA: 24 gate k-steps (2 indep chains) + 4 d k-steps ----
        f32x4 acc0 = {0.f, 0.f, 0.f, 0.f}, acc1 = {0.f, 0.f, 0.f, 0.f};
        f32x4 accd = {0.f, 0.f, 0.f, 0.f};
        #pragma unroll
        for (int i = 0; i < 12; ++i) {
            bf16x8 av = *(const bf16x8*)(h_sb + nn * 520 + i * 32 + q * 8);
            acc0 = __builtin_amdgcn_mfma_f32_16x16x32_bf16(av, bw[i], acc0, 0, 0, 0);
        }
        #pragma unroll
        for (int i = 12; i < 24; ++i) {
            const unsigned short* asrc = (i < 16)
                ? (h_sb + nn * 520 + i * 32 + q * 8)
                : (x_sb + nn * 264 + (i - 16) * 32 + q * 8);
            bf16x8 av = *(const bf16x8*)asrc;
            acc1 = __builtin_amdgcn_mfma_f32_16x16x32_bf16(av, bw[i], acc1, 0, 0, 0);
        }
        #pragma unroll
        for (int i = 0; i < 4; ++i) {
            const int kd = (w & 3) * 4 + i;
            bf16x8 av = *(const bf16x8*)(c_sb + nn * 520 + kd * 32 + q * 8);
            accd = __builtin_amdgcn_mfma_f32_16x16x32_bf16(av, bd[i], accd, 0, 0, 0);
        }

        // ---- gate activations in-register, spill act + Dred ----
        const int dt = w >> 2;
        #pragma unroll
        for (int rr = 0; rr < 4; ++rr) {
            const int m = q * 4 + rr;
            const float sv = acc0[rr] + acc1[rr] + bias_g;
            act[g * 512 + m * 32 + jj] =
                (g == 3) ? fast_tanh(sv) : fast_sigmoid(sv);
            Dred[dt][w & 3][m * 16 + ((nn + m) & 15)] = accd[rr];
        }
        __syncthreads();

        // ---- d reduce (4-way) + decay ----
        {
            const int sl = rm * 16 + ((rn + rm) & 15);
            const float sv = Dred[rtl][0][sl] + Dred[rtl][1][sl]
                           + Dred[rtl][2][sl] + Dred[rtl][3][sl];
            cs1v[rm * 32 + rtl * 16 + rn] = fast_tanh(sv + bias_d);
        }
        if (t < 8)
            decv[t] = 1.0f / __logf(2.7182818284590452f + ts[(b0 + t) * Sdim + s]);
        __syncthreads();

        // ---- finale: 256 units (8 batches x 32 cols) ----
        if (t < 256) {
            const float dec  = decv[fm];
            const float cs1  = cs1v[t];
            const float cadj = (c_reg - cs1) + cs1 * dec;
            const float f  = act[t];
            const float ii = act[512 + t];
            const float oo = act[1024 + t];
            const float gg = act[1536 + t];
            const float cn = f * cadj + ii * gg;
            const float hn = oo * fast_tanh(cn);
            c_reg = cn;
            out[((size_t)(b0 + fm) * Sdim + s) * Hdim + j0 + fj] = hn;
            const float hn1 = __shfl_down(hn, 1);
            const float cn1 = __shfl_down(cn, 1);
            if (s < Sdim - 1) {
                if ((t & 1) == 0) {
                    unsigned* hmw = (unsigned*)(ws + WS_HMIR0 + ((s + 1) & 1) * 65536);
                    unsigned* cmw = (unsigned*)(ws + WS_CMIR0 + ((s + 1) & 1) * 65536);
                    const int didx = ((b0 + fm) * Hdim + j0 + fj) >> 1;
                    if (fast) {   // plain write-through stores -> XCD L2
                        *(volatile unsigned*)(hmw + didx) = pack2(hn, hn1);
                        *(volatile unsigned*)(cmw + didx) = pack2(cn, cn1);
                    } else {
                        st_dev_u32(hmw + didx, pack2(hn, hn1));
                        st_dev_u32(cmw + didx, pack2(cn, cn1));
                    }
                }
            } else {
                float* hf = out + (size_t)Bdim * Sdim * Hdim;
                float* cf = hf + (size_t)Bdim * Hdim;
                hf[(b0 + fm) * Hdim + j0 + fj] = hn;
                cf[(b0 + fm) * Hdim + j0 + fj] = cn;
            }
        }

        if (s == Sdim - 1) break;

        __syncthreads();   // B: implicit vmcnt(0) drains mirror stores to L2
        if (t == 0) {
            unsigned* fp = (unsigned*)&flags[(bg * 16 + cg) * FSTR];
            if (fast) *(volatile unsigned*)fp = (unsigned)(s + 1);
            else      st_dev_u32(fp, (unsigned)(s + 1));
        }
        if (t < 256) stage_x(s + 1);   // overlaps flag propagation
        if (t < 16) {                  // 16-WG barrier within this group only
            const unsigned* fp = (const unsigned*)&flags[(bg * 16 + t) * FSTR];
            if (fast) {
                for (int it = 0; it < FPOLL_CAP; ++it) {
                    if ((int)ld_l2_u32(fp) >= s + 1) break;
                    __builtin_amdgcn_s_sleep(1);
                }
            } else {
                while ((int)ld_dev_u32(fp) < s + 1) __builtin_amdgcn_s_sleep(1);
            }
        }
        __syncthreads();   // C
    }
}

extern "C" void kernel_launch(void* const* d_in, const int* in_sizes, int n_in,
                              void* d_out, int out_size, void* d_ws, size_t ws_size,
                              hipStream_t stream) {
    const float* x      = (const float*)d_in[0];
    const float* ts     = (const float*)d_in[1];
    const float* Wall   = (const float*)d_in[2];
    const float* Wall_b = (const float*)d_in[3];
    const float* Uall   = (const float*)d_in[4];
    const float* Uall_b = (const float*)d_in[5];
    const float* Wd     = (const float*)d_in[6];
    const float* Wd_b   = (const float*)d_in[7];

    tlstm_prep<<<256, 256, 0, stream>>>(Wall, Uall, Wd, (unsigned char*)d_ws);
    tlstm_mfma<<<NWG, NT, 0, stream>>>(x, ts, Wall_b, Uall_b, Wd_b,
                                       (float*)d_out, (unsigned char*)d_ws);
}

// Round 8
// 1837.343 us; speedup vs baseline: 396.3716x; 396.3716x over previous
//
#include <hip/hip_runtime.h>
#include <cmath>

// TimeLSTMCell B=64, S=512, E=256, H=512.
// Round 12 (base = round-6 @2008us verbatim; r11's XCD-L2 path is DEAD —
// twice-confirmed that per-XCD L2s give no cross-WG coherence; MALL
// agent-scope is the only correct medium). Three scheduling cuts, no sync
// mechanism changes:
//   1. x-GEMM FIRST under the mirror-load RT: issue the 8 h/c mirror loads
//      into registers at loop top, run the 8 x-K-step MFMA chain (x_sb
//      already staged) while they fly, then commit h/c to LDS. Hides ~300cy
//      of the ~1000cy exposed load RT.
//   2. d-reduce + decay folded into the finale (own 4 Dred partials + own
//      logf per thread): one fewer barrier, no cs1v/decv round trip.
//   3. out[] HBM store AFTER the flag publish: pre-flag barrier drains only
//      the 2KB mirror stores; the HBM ack rides under the poll window and is
//      absorbed by the post-poll barrier.
// Barriers/step: 5 -> 4. Poll structure, mirror format, flag mechanics,
// weights-in-VGPR, frag layouts: r6 verbatim. absmax path identical (one
// benign accumulation-order change in acc1).
//
// MFMA 16x16x32 bf16 layouts (m89/m91/m120 verified):
//   A: m=lane&15, k=(lane>>4)*8+j   B: n=lane&15, k=(lane>>4)*8+j
//   D: n=lane&15, m=(lane>>4)*4+reg

typedef short bf16x8 __attribute__((ext_vector_type(8)));
typedef float f32x4  __attribute__((ext_vector_type(4)));

#define Bdim 64
#define Sdim 512
#define Edim 256
#define Hdim 512
#define NWG  64
#define NT   512
#define FSTR 16

// ws layout (bytes), identical to round 6. Total ~3.95 MB.
#define WS_FLAGS 0
#define WS_HMIR0 16384
#define WS_HMIR1 (WS_HMIR0 + 65536)
#define WS_CMIR0 (WS_HMIR1 + 65536)
#define WS_CMIR1 (WS_CMIR0 + 65536)
#define WS_WFRAG (WS_CMIR1 + 65536)       // 16cg*8wv*24k*64lane*8 bf16 = 3 MB
#define WS_DFRAG (WS_WFRAG + 3145728)     // 16cg*8wv*4k*64lane*8 bf16 = 512 KB

__device__ __forceinline__ unsigned ld_dev_u32(const unsigned* p) {
    return __hip_atomic_load(p, __ATOMIC_RELAXED, __HIP_MEMORY_SCOPE_AGENT);
}
__device__ __forceinline__ void st_dev_u32(unsigned* p, unsigned v) {
    __hip_atomic_store(p, v, __ATOMIC_RELAXED, __HIP_MEMORY_SCOPE_AGENT);
}
__device__ __forceinline__ unsigned long long ld_dev_u64(const unsigned long long* p) {
    return __hip_atomic_load(p, __ATOMIC_RELAXED, __HIP_MEMORY_SCOPE_AGENT);
}
__device__ __forceinline__ unsigned short f2bf(float f) {
    union { float f; unsigned u; } v; v.f = f;
    return (unsigned short)((v.u + 0x7FFFu + ((v.u >> 16) & 1u)) >> 16);  // RNE
}
__device__ __forceinline__ unsigned pack2(float lo, float hi) {
    return (unsigned)f2bf(lo) | ((unsigned)f2bf(hi) << 16);
}
__device__ __forceinline__ float fast_tanh(float x) {
    const float ax = __builtin_fabsf(x);
    const float e  = __expf(-2.0f * ax);
    const float t  = (1.0f - e) / (1.0f + e);
    return __builtin_copysignf(t, x);
}
__device__ __forceinline__ float fast_sigmoid(float x) {
    return 1.0f / (1.0f + __expf(-x));
}

// ---------------- pre-pass: pack weights, zero mirrors/flags ----------------
// (verbatim round 6 — frag layouts unchanged)
__global__ __launch_bounds__(256) void tlstm_prep(
    const float* __restrict__ Wall, const float* __restrict__ Uall,
    const float* __restrict__ Wd, unsigned char* __restrict__ ws)
{
    const int w = blockIdx.x, t = threadIdx.x;
    unsigned short* Wfrag = (unsigned short*)(ws + WS_WFRAG);
    unsigned short* Dfrag = (unsigned short*)(ws + WS_DFRAG);
    const int l = t & 63, ks = t >> 6, nn = l & 15, q = l >> 4;

    if (w < 128) {                       // gate fragments: WG = (cg, wv)
        const int cg = w >> 3, wv = w & 7;
        const int G = wv * 16 + nn, g = G >> 5, jj = G & 31;
        const int row = g * Hdim + cg * 32 + jj;
        for (int i = 0; i < 6; ++i) {
            const int kp = ks * 6 + i;   // 0..23
            const float* src = (kp < 16)
                ? Wall + (size_t)row * Hdim + kp * 32 + q * 8
                : Uall + (size_t)row * Edim + (kp - 16) * 32 + q * 8;
            unsigned* dst = (unsigned*)(Wfrag
                + (((size_t)(cg * 8 + wv) * 24 + kp) * 64 + l) * 8);
            #pragma unroll
            for (int p = 0; p < 4; ++p) dst[p] = pack2(src[2*p], src[2*p+1]);
        }
    } else if (w < 192) {                // d fragments: 64 WGs, 8 frags each
        const int u = w - 128, cg = u >> 2, q4 = u & 3;
        for (int half = 0; half < 2; ++half) {
            const int wv = q4 * 2 + half;        // 0..7
            const int i  = ks;                   // 0..3
            const int dt = wv >> 2, kd = (wv & 3) * 4 + i;
            const int row = cg * 32 + dt * 16 + nn;     // Wd output col
            const float* src = Wd + (size_t)row * Hdim + kd * 32 + q * 8;
            unsigned* dst = (unsigned*)(Dfrag
                + (((size_t)(cg * 8 + wv) * 4 + i) * 64 + l) * 8);
            #pragma unroll
            for (int p = 0; p < 4; ++p) dst[p] = pack2(src[2*p], src[2*p+1]);
        }
    } else {                             // zero flags + all 4 mirrors (278528 B)
        const int idx = (w - 192) * 256 + t;          // 0..16383
        uint4* z = (uint4*)ws;
        for (int i = idx; i < 17408; i += 16384) z[i] = make_uint4(0, 0, 0, 0);
        // mirror parity-0 zeros ARE the valid step-0 state (h=c=0).
    }
}

// ------------------------------- main kernel --------------------------------
__global__ __launch_bounds__(NT, 2) void tlstm_mfma(
    const float* __restrict__ x,       // [B,S,E] fp32
    const float* __restrict__ ts,      // [B,S]
    const float* __restrict__ Wall_b,  // [4H]
    const float* __restrict__ Uall_b,  // [4H]
    const float* __restrict__ Wd_b,    // [H]
    float* __restrict__ out,           // [B,S,H] | h_f | c_f (write-only)
    unsigned char* __restrict__ ws)
{
    __shared__ __align__(16) unsigned short h_sb[16 * 520];   // bf16, row pad +8
    __shared__ __align__(16) unsigned short c_sb[16 * 520];
    __shared__ __align__(16) unsigned short x_sb[16 * 264];
    __shared__ float Dred[2][4][256];
    __shared__ float act[4 * 512];              // [gate][m*32+jj]

    int* flags = (int*)(ws + WS_FLAGS);
    const unsigned short* Wfrag = (const unsigned short*)(ws + WS_WFRAG);
    const unsigned short* Dfrag = (const unsigned short*)(ws + WS_DFRAG);

    const int t    = threadIdx.x;
    const int bg   = blockIdx.x >> 4, cg = blockIdx.x & 15;
    const int b0   = bg * 16, j0 = cg * 32;
    const int w    = t >> 6, lane = t & 63, q = lane >> 4, nn = lane & 15;

    // gate-col identity of this lane (wave w owns gate-col tile w: 16 cols)
    const int G = w * 16 + nn, g = G >> 5, jj = G & 31;
    const float bias_g = Wall_b[g * Hdim + j0 + jj] + Uall_b[g * Hdim + j0 + jj];
    // finale identity: unit t -> (batch fm, col fj); d-reduce folded in
    const int fm = t >> 5, fj = t & 31;
    const int fdt = fj >> 4, fn = fj & 15;
    const float bias_d = Wd_b[j0 + fj];

    // ---- weights -> registers, once (L2-hot loads; r6 layout) ----
    bf16x8 bw[24];
    #pragma unroll
    for (int i = 0; i < 24; ++i)
        bw[i] = *(const bf16x8*)(Wfrag
            + (((size_t)(cg * 8 + w) * 24 + i) * 64 + lane) * 8);
    bf16x8 bd[4];
    #pragma unroll
    for (int i = 0; i < 4; ++i)
        bd[i] = *(const bf16x8*)(Dfrag
            + (((size_t)(cg * 8 + w) * 4 + i) * 64 + lane) * 8);

    const int srow = t >> 5, sc32 = t & 31;    // staging role: row, chunk

    // stage x[b0..b0+16, sx, :] -> x_sb (plain cached loads, fp32 -> bf16)
    auto stage_x = [&](int sx) {
        const float4* xp = (const float4*)(x + ((size_t)(b0 + srow) * Sdim + sx) * Edim + sc32 * 8);
        float4 v0 = xp[0], v1 = xp[1];
        *(uint4*)((unsigned*)x_sb + srow * 132 + sc32 * 4) =
            make_uint4(pack2(v0.x, v0.y), pack2(v0.z, v0.w),
                       pack2(v1.x, v1.y), pack2(v1.z, v1.w));
    };

    stage_x(0);
    float c_reg = 0.0f;                        // fp32 c carry for own unit
    __syncthreads();

    for (int s = 0;; ++s) {
        // ---- issue h/c mirror loads into registers (MALL RT starts) ----
        const unsigned long long* hsrc =
            (const unsigned long long*)(ws + WS_HMIR0 + (s & 1) * 65536);
        const unsigned long long* csrc =
            (const unsigned long long*)(ws + WS_CMIR0 + (s & 1) * 65536);
        const size_t goff = (size_t)(b0 + srow) * 128 + sc32 * 4;  // u64 index
        unsigned long long hv[4], cv[4];
        #pragma unroll
        for (int i = 0; i < 4; ++i) hv[i] = ld_dev_u64(hsrc + goff + i);
        #pragma unroll
        for (int i = 0; i < 4; ++i) cv[i] = ld_dev_u64(csrc + goff + i);

        // ---- x-chain (8 MFMAs) runs while the mirror loads fly ----
        f32x4 acc1 = {0.f, 0.f, 0.f, 0.f};
        #pragma unroll
        for (int i = 16; i < 24; ++i) {
            bf16x8 av = *(const bf16x8*)(x_sb + nn * 264 + (i - 16) * 32 + q * 8);
            acc1 = __builtin_amdgcn_mfma_f32_16x16x32_bf16(av, bw[i], acc1, 0, 0, 0);
        }

        // ---- commit h/c to LDS (compiler waits the loads here) ----
        {
            unsigned* hls = (unsigned*)h_sb + srow * 260 + sc32 * 8;
            unsigned* cls = (unsigned*)c_sb + srow * 260 + sc32 * 8;
            ((ulonglong2*)hls)[0] = make_ulonglong2(hv[0], hv[1]);
            ((ulonglong2*)hls)[1] = make_ulonglong2(hv[2], hv[3]);
            ((ulonglong2*)cls)[0] = make_ulonglong2(cv[0], cv[1]);
            ((ulonglong2*)cls)[1] = make_ulonglong2(cv[2], cv[3]);
        }
        __syncthreads();                                   // (1)

        // ---- h-chains (16 MFMAs) + d-chain (4 MFMAs) ----
        f32x4 acc0 = {0.f, 0.f, 0.f, 0.f};
        f32x4 accd = {0.f, 0.f, 0.f, 0.f};
        #pragma unroll
        for (int i = 0; i < 12; ++i) {
            bf16x8 av = *(const bf16x8*)(h_sb + nn * 520 + i * 32 + q * 8);
            acc0 = __builtin_amdgcn_mfma_f32_16x16x32_bf16(av, bw[i], acc0, 0, 0, 0);
        }
        #pragma unroll
        for (int i = 12; i < 16; ++i) {
            bf16x8 av = *(const bf16x8*)(h_sb + nn * 520 + i * 32 + q * 8);
            acc1 = __builtin_amdgcn_mfma_f32_16x16x32_bf16(av, bw[i], acc1, 0, 0, 0);
        }
        #pragma unroll
        for (int i = 0; i < 4; ++i) {
            const int kd = (w & 3) * 4 + i;
            bf16x8 av = *(const bf16x8*)(c_sb + nn * 520 + kd * 32 + q * 8);
            accd = __builtin_amdgcn_mfma_f32_16x16x32_bf16(av, bd[i], accd, 0, 0, 0);
        }

        // ---- gate activations in-register, spill act + Dred ----
        const int dt = w >> 2;
        #pragma unroll
        for (int rr = 0; rr < 4; ++rr) {
            const int m = q * 4 + rr;
            const float sv = acc0[rr] + acc1[rr] + bias_g;
            act[g * 512 + m * 32 + jj] =
                (g == 3) ? fast_tanh(sv) : fast_sigmoid(sv);
            Dred[dt][w & 3][m * 16 + ((nn + m) & 15)] = accd[rr];
        }
        __syncthreads();                                   // (2)

        // ---- finale: 512 units; d-reduce + decay folded in ----
        float hn;
        size_t out_idx;
        {
            const int sl = fm * 16 + ((fn + fm) & 15);
            const float dsum = Dred[fdt][0][sl] + Dred[fdt][1][sl]
                             + Dred[fdt][2][sl] + Dred[fdt][3][sl];
            const float cs1  = fast_tanh(dsum + bias_d);
            const float dec  = 1.0f / __logf(2.7182818284590452f
                                             + ts[(size_t)(b0 + fm) * Sdim + s]);
            const float cadj = (c_reg - cs1) + cs1 * dec;
            const float f  = act[t];
            const float ii = act[512 + t];
            const float oo = act[1024 + t];
            const float gg = act[1536 + t];
            const float cn = f * cadj + ii * gg;
            hn = oo * fast_tanh(cn);
            c_reg = cn;
            out_idx = ((size_t)(b0 + fm) * Sdim + s) * Hdim + j0 + fj;
            const float hn1 = __shfl_down(hn, 1);
            const float cn1 = __shfl_down(cn, 1);
            if (s < Sdim - 1) {
                if ((t & 1) == 0) {
                    unsigned* hmw = (unsigned*)(ws + WS_HMIR0 + ((s + 1) & 1) * 65536);
                    unsigned* cmw = (unsigned*)(ws + WS_CMIR0 + ((s + 1) & 1) * 65536);
                    const int didx = ((b0 + fm) * Hdim + j0 + fj) >> 1;
                    st_dev_u32(hmw + didx, pack2(hn, hn1));
                    st_dev_u32(cmw + didx, pack2(cn, cn1));
                }
            } else {
                out[out_idx] = hn;
                float* hf = out + (size_t)Bdim * Sdim * Hdim;
                float* cf = hf + (size_t)Bdim * Hdim;
                hf[(b0 + fm) * Hdim + j0 + fj] = hn;
                cf[(b0 + fm) * Hdim + j0 + fj] = cn;
            }
        }

        if (s == Sdim - 1) break;

        __syncthreads();   // (3): implicit vmcnt(0) drains ONLY mirror stores
        if (t == 0)
            st_dev_u32((unsigned*)&flags[(bg * 16 + cg) * FSTR],
                       (unsigned)(s + 1));
        out[out_idx] = hn;        // deferred HBM store: ack rides under poll
        stage_x(s + 1);           // cached loads, overlaps flag propagation
        if (t < 16) {             // 16-WG barrier within this bg group only
            while (__hip_atomic_load(&flags[(bg * 16 + t) * FSTR],
                                     __ATOMIC_RELAXED,
                                     __HIP_MEMORY_SCOPE_AGENT) < s + 1) {
                __builtin_amdgcn_s_sleep(1);
            }
        }
        __syncthreads();          // (4): absorbs out-store ack + stage_x
    }
}

extern "C" void kernel_launch(void* const* d_in, const int* in_sizes, int n_in,
                              void* d_out, int out_size, void* d_ws, size_t ws_size,
                              hipStream_t stream) {
    const float* x      = (const float*)d_in[0];
    const float* ts     = (const float*)d_in[1];
    const float* Wall   = (const float*)d_in[2];
    const float* Wall_b = (const float*)d_in[3];
    const float* Uall   = (const float*)d_in[4];
    const float* Uall_b = (const float*)d_in[5];
    const float* Wd     = (const float*)d_in[6];
    const float* Wd_b   = (const float*)d_in[7];

    tlstm_prep<<<256, 256, 0, stream>>>(Wall, Uall, Wd, (unsigned char*)d_ws);
    tlstm_mfma<<<NWG, NT, 0, stream>>>(x, ts, Wall_b, Uall_b, Wd_b,
                                       (float*)d_out, (unsigned char*)d_ws);
}